// Round 3
// baseline (161.233 us; speedup 1.0000x reference)
//
#include <hip/hip_runtime.h>

// LiftSplatShoot: frustum geometry -> voxel scatter-add.
// Geometry computed in FLOAT64, matching the harness's numpy float64
// reference ("ref=np"). At f64 precision, op ordering is irrelevant:
// voxel-boundary distances (~1e-5 rel) >> f64 noise (~1e-16 rel).
// Wave layout: one wave = one (b,n,d,w) with lanes = 64 channels.
// Lanes 0..15 compute the f64 chain for h=lane; addr broadcast via shfl.

#define FHH 16
#define FWW 44
#define NDD 41
#define NCAM 6
#define NB 4
#define NC 64
#define NX0 200
#define NX1 200

// 3x3 inverse in double: LU with partial pivoting + triangular solves.
__device__ void lu_inv3d(const double A[3][3], double out[3][3]) {
  double M[3][3]; int piv[3] = {0,1,2};
  for (int i=0;i<3;i++) for (int j=0;j<3;j++) M[i][j]=A[i][j];
  for (int k=0;k<3;k++){
    int p=k; double mx=fabs(M[k][k]);
    for (int r=k+1;r<3;r++){ double v=fabs(M[r][k]); if (v>mx){mx=v;p=r;} }
    if (p!=k){
      for (int j=0;j<3;j++){ double t=M[k][j]; M[k][j]=M[p][j]; M[p][j]=t; }
      int t=piv[k]; piv[k]=piv[p]; piv[p]=t;
    }
    for (int r=k+1;r<3;r++){
      double l = M[r][k] / M[k][k];
      M[r][k]=l;
      for (int j=k+1;j<3;j++) M[r][j] -= l*M[k][j];
    }
  }
  for (int col=0; col<3; col++){
    double bb[3];
    for (int i=0;i<3;i++) bb[i] = (piv[i]==col) ? 1.0 : 0.0;
    for (int i=1;i<3;i++){
      double acc=bb[i];
      for (int j=0;j<i;j++) acc -= M[i][j]*bb[j];
      bb[i]=acc;
    }
    for (int i=2;i>=0;i--){
      double acc=bb[i];
      for (int j=i+1;j<3;j++) acc -= M[i][j]*bb[j];
      bb[i]=acc / M[i][i];
    }
    out[0][col]=bb[0]; out[1][col]=bb[1]; out[2][col]=bb[2];
  }
}

__global__ __launch_bounds__(256) void lss_scatter_kernel(
    const float* __restrict__ x_img, const float* __restrict__ rots,
    const float* __restrict__ trans, const float* __restrict__ intrins,
    const float* __restrict__ post_rots, const float* __restrict__ post_trans,
    float* __restrict__ out)
{
  const int slab = blockIdx.x / 11;        // (b,n,d) index, 984 slabs
  const int sub  = blockIdx.x % 11;
  const int t = sub*256 + (int)threadIdx.x;    // 0..2815
  const int w = t >> 6;                    // 0..43 (one wave per w)
  const int c = t & 63;                    // channel = lane
  const int b = slab / (NCAM*NDD);
  const int rem = slab % (NCAM*NDD);
  const int n = rem / NDD;
  const int d = rem % NDD;
  const int bn = b*NCAM + n;
  const int lane = c;

  int myAddr = -1;                         // voxel addr for h = lane (lanes 0..15)
  if (lane < FHH) {
    const float* Rp  = rots      + bn*9;
    const float* Kp  = intrins   + bn*9;
    const float* Pp  = post_rots + bn*9;
    const float* Tp  = trans     + bn*3;
    const float* PTp = post_trans+ bn*3;

    double R[3][3], K[3][3], PR[3][3];
    for (int i=0;i<3;i++) for (int j=0;j<3;j++){
      R[i][j]=(double)Rp[i*3+j]; K[i][j]=(double)Kp[i*3+j]; PR[i][j]=(double)Pp[i*3+j];
    }
    double iK[3][3], iPR[3][3];
    lu_inv3d(K, iK);
    lu_inv3d(PR, iPR);

    double C[3][3];
    for (int i=0;i<3;i++) for (int j=0;j<3;j++)
      C[i][j] = R[i][0]*iK[0][j] + R[i][1]*iK[1][j] + R[i][2]*iK[2][j];

    const double T0=(double)Tp[0], T1=(double)Tp[1], T2=(double)Tp[2];
    const double P0=(double)PTp[0], P1=(double)PTp[1], P2=(double)PTp[2];

    const double u  = (double)w * (703.0/43.0);   // xs[w]
    const double v  = (double)lane * 17.0;        // ys[h], h = lane
    const double dd = (double)(4 + d);

    const double p0x = u  - P0;
    const double p0y = v  - P1;
    const double p0z = dd - P2;
    const double p1x = iPR[0][0]*p0x + iPR[0][1]*p0y + iPR[0][2]*p0z;
    const double p1y = iPR[1][0]*p0x + iPR[1][1]*p0y + iPR[1][2]*p0z;
    const double p1z = iPR[2][0]*p0x + iPR[2][1]*p0y + iPR[2][2]*p0z;
    const double p2x = p1x * p1z;
    const double p2y = p1y * p1z;
    const double p2z = p1z;
    const double gx = C[0][0]*p2x + C[0][1]*p2y + C[0][2]*p2z + T0;
    const double gy = C[1][0]*p2x + C[1][1]*p2y + C[1][2]*p2z + T1;
    const double gz = C[2][0]*p2x + C[2][1]*p2y + C[2][2]*p2z + T2;

    const double tx = (gx + 50.0) / 0.5;
    const double ty = (gy + 50.0) / 0.5;
    const double tz = (gz + 10.0) / 20.0;
    const int ix = (int)tx;                 // trunc toward zero == astype(int32)
    const int iy = (int)ty;
    const int iz = (int)tz;                 // note: (-1,0) range truncates to 0 -> kept
    const bool kept = (ix>=0) && (ix<NX0) && (iy>=0) && (iy<NX1) && (iz==0);
    myAddr = kept ? (((b*NC)*NX1 + iy)*NX0 + ix) : -1;   // c added per-lane below
  }

  const float* featbase = x_img + (size_t)(((size_t)bn*NDD + d)*FHH*FWW)*NC;

  int prevAddr = -1;
  float acc = 0.0f;
  const int cOff = c * NX1 * NX0;

  #pragma unroll
  for (int h=0; h<FHH; h++){
    int a = __shfl(myAddr, h, 64);          // base addr (c=0) for this h
    const int addr = (a >= 0) ? (a + cOff) : -1;
    if (addr != prevAddr){
      if (prevAddr >= 0) atomicAdd(out + prevAddr, acc);
      acc = 0.0f;
      prevAddr = addr;
    }
    if (addr >= 0){
      acc += featbase[((size_t)(h*FWW + w) << 6) + c];
    }
  }
  if (prevAddr >= 0) atomicAdd(out + prevAddr, acc);
}

extern "C" void kernel_launch(void* const* d_in, const int* in_sizes, int n_in,
                              void* d_out, int out_size, void* d_ws, size_t ws_size,
                              hipStream_t stream) {
  const float* x_img      = (const float*)d_in[0];
  const float* rots       = (const float*)d_in[1];
  const float* trans      = (const float*)d_in[2];
  const float* intrins    = (const float*)d_in[3];
  const float* post_rots  = (const float*)d_in[4];
  const float* post_trans = (const float*)d_in[5];
  float* out = (float*)d_out;

  hipMemsetAsync(out, 0, (size_t)out_size * sizeof(float), stream);

  const int slabs = NB*NCAM*NDD;           // 984
  dim3 grid(slabs * 11), block(256);
  lss_scatter_kernel<<<grid, block, 0, stream>>>(
      x_img, rots, trans, intrins, post_rots, post_trans, out);
}

// Round 4
// 153.223 us; speedup vs baseline: 1.0523x; 1.0523x over previous
//
#include <hip/hip_runtime.h>

// LiftSplatShoot: frustum geometry -> voxel scatter-add.
// f64 geometry (matches numpy f64 reference; voxel-boundary distances >> f64 noise).
// k0: per-(b,n) matrix precompute (C = R*inv(K), inv(post_rots)) -> d_ws.
// k1: scatter. One wave per (b,n,d,w); lanes = 64 channels.
//     Lanes 0..15 compute the f64 point transform for h=lane -> voxel addr.
//     Early-exit if no h kept. 16 pipelined feature loads, register run-length
//     merge, one atomicAdd per (lane, voxel-run).

#define FHH 16
#define FWW 44
#define NDD 41
#define NCAM 6
#define NB 4
#define NC 64
#define NX0 200
#define NX1 200

// 3x3 inverse in double: LU with partial pivoting + triangular solves.
__device__ void lu_inv3d(const double A[3][3], double out[3][3]) {
  double M[3][3]; int piv[3] = {0,1,2};
  for (int i=0;i<3;i++) for (int j=0;j<3;j++) M[i][j]=A[i][j];
  for (int k=0;k<3;k++){
    int p=k; double mx=fabs(M[k][k]);
    for (int r=k+1;r<3;r++){ double v=fabs(M[r][k]); if (v>mx){mx=v;p=r;} }
    if (p!=k){
      for (int j=0;j<3;j++){ double t=M[k][j]; M[k][j]=M[p][j]; M[p][j]=t; }
      int t=piv[k]; piv[k]=piv[p]; piv[p]=t;
    }
    for (int r=k+1;r<3;r++){
      double l = M[r][k] / M[k][k];
      M[r][k]=l;
      for (int j=k+1;j<3;j++) M[r][j] -= l*M[k][j];
    }
  }
  for (int col=0; col<3; col++){
    double bb[3];
    for (int i=0;i<3;i++) bb[i] = (piv[i]==col) ? 1.0 : 0.0;
    for (int i=1;i<3;i++){
      double acc=bb[i];
      for (int j=0;j<i;j++) acc -= M[i][j]*bb[j];
      bb[i]=acc;
    }
    for (int i=2;i>=0;i--){
      double acc=bb[i];
      for (int j=i+1;j<3;j++) acc -= M[i][j]*bb[j];
      bb[i]=acc / M[i][i];
    }
    out[0][col]=bb[0]; out[1][col]=bb[1]; out[2][col]=bb[2];
  }
}

// ws layout per bn (24 doubles): C[9], iPR[9], T[3], P[3]
__global__ __launch_bounds__(64) void lss_precompute_kernel(
    const float* __restrict__ rots, const float* __restrict__ intrins,
    const float* __restrict__ post_rots, const float* __restrict__ trans,
    const float* __restrict__ post_trans, double* __restrict__ ws)
{
  const int bn = threadIdx.x;
  if (bn >= NB*NCAM) return;
  double R[3][3], K[3][3], PR[3][3];
  for (int i=0;i<3;i++) for (int j=0;j<3;j++){
    R[i][j]=(double)rots[bn*9+i*3+j];
    K[i][j]=(double)intrins[bn*9+i*3+j];
    PR[i][j]=(double)post_rots[bn*9+i*3+j];
  }
  double iK[3][3], iPR[3][3];
  lu_inv3d(K, iK);
  lu_inv3d(PR, iPR);
  double* W = ws + bn*24;
  for (int i=0;i<3;i++) for (int j=0;j<3;j++){
    W[i*3+j]   = R[i][0]*iK[0][j] + R[i][1]*iK[1][j] + R[i][2]*iK[2][j]; // C
    W[9+i*3+j] = iPR[i][j];
  }
  for (int i=0;i<3;i++){
    W[18+i] = (double)trans[bn*3+i];
    W[21+i] = (double)post_trans[bn*3+i];
  }
}

__global__ __launch_bounds__(256) void lss_scatter_kernel(
    const float* __restrict__ x_img, const double* __restrict__ ws,
    float* __restrict__ out)
{
  const int slab = blockIdx.x / 11;        // (b,n,d) index, 984 slabs
  const int sub  = blockIdx.x % 11;
  const int t = sub*256 + (int)threadIdx.x;    // 0..2815
  const int w = t >> 6;                    // 0..43 (one wave per w)
  const int c = t & 63;                    // channel = lane
  const int b = slab / (NCAM*NDD);
  const int rem = slab % (NCAM*NDD);
  const int n = rem / NDD;
  const int d = rem % NDD;
  const int bn = b*NCAM + n;
  const int lane = c;

  int myAddr = -1;                         // voxel addr (c=0) for h = lane
  if (lane < FHH) {
    const double* W = ws + bn*24;
    const double u  = (double)w * (703.0/43.0);   // xs[w]
    const double v  = (double)lane * 17.0;        // ys[h]
    const double dd = (double)(4 + d);

    const double p0x = u  - W[21];
    const double p0y = v  - W[22];
    const double p0z = dd - W[23];
    const double p1x = W[9+0]*p0x + W[9+1]*p0y + W[9+2]*p0z;
    const double p1y = W[9+3]*p0x + W[9+4]*p0y + W[9+5]*p0z;
    const double p1z = W[9+6]*p0x + W[9+7]*p0y + W[9+8]*p0z;
    const double p2x = p1x * p1z;
    const double p2y = p1y * p1z;
    const double p2z = p1z;
    const double gx = W[0]*p2x + W[1]*p2y + W[2]*p2z + W[18];
    const double gy = W[3]*p2x + W[4]*p2y + W[5]*p2z + W[19];
    const double gz = W[6]*p2x + W[7]*p2y + W[8]*p2z + W[20];

    const double tx = (gx + 50.0) / 0.5;
    const double ty = (gy + 50.0) / 0.5;
    const double tz = (gz + 10.0) / 20.0;
    const int ix = (int)tx;                 // trunc toward zero == astype(int32)
    const int iy = (int)ty;
    const int iz = (int)tz;
    const bool kept = (ix>=0) && (ix<NX0) && (iy>=0) && (iy<NX1) && (iz==0);
    myAddr = kept ? (((b*NC)*NX1 + iy)*NX0 + ix) : -1;
  }

  // whole-wave early exit: no h kept -> nothing to read or write
  if (__ballot(myAddr >= 0) == 0ull) return;

  const float* featbase = x_img + (size_t)(((size_t)bn*NDD + d)*FHH*FWW)*NC
                        + ((size_t)w << 6) + c;

  // phase 1: issue all 16 loads back-to-back (independent, coalesced per wave)
  float f[FHH];
  #pragma unroll
  for (int h=0; h<FHH; h++)
    f[h] = featbase[(size_t)h * (FWW*NC)];

  // phase 2: register run-length merge + atomics
  const int cOff = c * NX1 * NX0;
  int prevAddr = -1;
  float acc = 0.0f;
  #pragma unroll
  for (int h=0; h<FHH; h++){
    const int a = __shfl(myAddr, h, 64);
    const int addr = (a >= 0) ? (a + cOff) : -1;
    if (addr != prevAddr){
      if (prevAddr >= 0) atomicAdd(out + prevAddr, acc);
      acc = 0.0f;
      prevAddr = addr;
    }
    if (addr >= 0) acc += f[h];
  }
  if (prevAddr >= 0) atomicAdd(out + prevAddr, acc);
}

extern "C" void kernel_launch(void* const* d_in, const int* in_sizes, int n_in,
                              void* d_out, int out_size, void* d_ws, size_t ws_size,
                              hipStream_t stream) {
  const float* x_img      = (const float*)d_in[0];
  const float* rots       = (const float*)d_in[1];
  const float* trans      = (const float*)d_in[2];
  const float* intrins    = (const float*)d_in[3];
  const float* post_rots  = (const float*)d_in[4];
  const float* post_trans = (const float*)d_in[5];
  float* out = (float*)d_out;
  double* ws = (double*)d_ws;

  hipMemsetAsync(out, 0, (size_t)out_size * sizeof(float), stream);

  lss_precompute_kernel<<<1, 64, 0, stream>>>(rots, intrins, post_rots,
                                              trans, post_trans, ws);

  const int slabs = NB*NCAM*NDD;           // 984
  dim3 grid(slabs * 11), block(256);
  lss_scatter_kernel<<<grid, block, 0, stream>>>(x_img, ws, out);
}

// Round 5
// 62.465 us; speedup vs baseline: 2.5812x; 2.4529x over previous
//
#include <hip/hip_runtime.h>

// LiftSplatShoot: frustum geometry -> voxel scatter-add.
// f64 geometry (matches numpy f64 ref). Three-phase:
//   k0: per-(b,n) matrix precompute -> ws[0..575]
//   k1: scatter into channel-fast scratch grid (b,iy,ix,c) — 64-lane atomic
//       bursts hit 2 cache lines instead of 64 (coalesced atomics).
//   k2: LDS transpose scratch(b,v,c) -> out(b,c,v); writes all of out.
// Fallback (small ws): direct atomics into out (R4 path).

#define FHH 16
#define FWW 44
#define NDD 41
#define NCAM 6
#define NB 4
#define NC 64
#define NX0 200
#define NX1 200
#define NVOX (NX0*NX1)
#define SCRATCH_OFF_BYTES 8192

// 3x3 inverse in double: LU with partial pivoting + triangular solves.
__device__ void lu_inv3d(const double A[3][3], double out[3][3]) {
  double M[3][3]; int piv[3] = {0,1,2};
  for (int i=0;i<3;i++) for (int j=0;j<3;j++) M[i][j]=A[i][j];
  for (int k=0;k<3;k++){
    int p=k; double mx=fabs(M[k][k]);
    for (int r=k+1;r<3;r++){ double v=fabs(M[r][k]); if (v>mx){mx=v;p=r;} }
    if (p!=k){
      for (int j=0;j<3;j++){ double t=M[k][j]; M[k][j]=M[p][j]; M[p][j]=t; }
      int t=piv[k]; piv[k]=piv[p]; piv[p]=t;
    }
    for (int r=k+1;r<3;r++){
      double l = M[r][k] / M[k][k];
      M[r][k]=l;
      for (int j=k+1;j<3;j++) M[r][j] -= l*M[k][j];
    }
  }
  for (int col=0; col<3; col++){
    double bb[3];
    for (int i=0;i<3;i++) bb[i] = (piv[i]==col) ? 1.0 : 0.0;
    for (int i=1;i<3;i++){
      double acc=bb[i];
      for (int j=0;j<i;j++) acc -= M[i][j]*bb[j];
      bb[i]=acc;
    }
    for (int i=2;i>=0;i--){
      double acc=bb[i];
      for (int j=i+1;j<3;j++) acc -= M[i][j]*bb[j];
      bb[i]=acc / M[i][i];
    }
    out[0][col]=bb[0]; out[1][col]=bb[1]; out[2][col]=bb[2];
  }
}

// ws layout per bn (24 doubles): C[9], iPR[9], T[3], P[3]
__global__ __launch_bounds__(64) void lss_precompute_kernel(
    const float* __restrict__ rots, const float* __restrict__ intrins,
    const float* __restrict__ post_rots, const float* __restrict__ trans,
    const float* __restrict__ post_trans, double* __restrict__ ws)
{
  const int bn = threadIdx.x;
  if (bn >= NB*NCAM) return;
  double R[3][3], K[3][3], PR[3][3];
  for (int i=0;i<3;i++) for (int j=0;j<3;j++){
    R[i][j]=(double)rots[bn*9+i*3+j];
    K[i][j]=(double)intrins[bn*9+i*3+j];
    PR[i][j]=(double)post_rots[bn*9+i*3+j];
  }
  double iK[3][3], iPR[3][3];
  lu_inv3d(K, iK);
  lu_inv3d(PR, iPR);
  double* W = ws + bn*24;
  for (int i=0;i<3;i++) for (int j=0;j<3;j++){
    W[i*3+j]   = R[i][0]*iK[0][j] + R[i][1]*iK[1][j] + R[i][2]*iK[2][j]; // C
    W[9+i*3+j] = iPR[i][j];
  }
  for (int i=0;i<3;i++){
    W[18+i] = (double)trans[bn*3+i];
    W[21+i] = (double)post_trans[bn*3+i];
  }
}

// Computes spatial voxel index (b*NX1+iy)*NX0+ix for h=lane (lanes 0..15), else -1.
__device__ __forceinline__ int voxel_addr_for_lane(
    const double* __restrict__ ws, int bn, int b, int d, int w, int lane)
{
  if (lane >= FHH) return -1;
  const double* W = ws + bn*24;
  const double u  = (double)w * (703.0/43.0);
  const double v  = (double)lane * 17.0;
  const double dd = (double)(4 + d);
  const double p0x = u  - W[21];
  const double p0y = v  - W[22];
  const double p0z = dd - W[23];
  const double p1x = W[9+0]*p0x + W[9+1]*p0y + W[9+2]*p0z;
  const double p1y = W[9+3]*p0x + W[9+4]*p0y + W[9+5]*p0z;
  const double p1z = W[9+6]*p0x + W[9+7]*p0y + W[9+8]*p0z;
  const double p2x = p1x * p1z;
  const double p2y = p1y * p1z;
  const double p2z = p1z;
  const double gx = W[0]*p2x + W[1]*p2y + W[2]*p2z + W[18];
  const double gy = W[3]*p2x + W[4]*p2y + W[5]*p2z + W[19];
  const double gz = W[6]*p2x + W[7]*p2y + W[8]*p2z + W[20];
  const double tx = (gx + 50.0) / 0.5;
  const double ty = (gy + 50.0) / 0.5;
  const double tz = (gz + 10.0) / 20.0;
  const int ix = (int)tx;
  const int iy = (int)ty;
  const int iz = (int)tz;
  const bool kept = (ix>=0) && (ix<NX0) && (iy>=0) && (iy<NX1) && (iz==0);
  return kept ? ((b*NX1 + iy)*NX0 + ix) : -1;
}

// Scatter into channel-fast scratch: scratch[(vox<<6)+c]
__global__ __launch_bounds__(256) void lss_scatter_cf_kernel(
    const float* __restrict__ x_img, const double* __restrict__ ws,
    float* __restrict__ scratch)
{
  const int slab = blockIdx.x / 11;
  const int sub  = blockIdx.x % 11;
  const int t = sub*256 + (int)threadIdx.x;
  const int w = t >> 6;
  const int c = t & 63;
  const int b = slab / (NCAM*NDD);
  const int rem = slab % (NCAM*NDD);
  const int n = rem / NDD;
  const int d = rem % NDD;
  const int bn = b*NCAM + n;

  const int myAddr = voxel_addr_for_lane(ws, bn, b, d, w, c);
  if (__ballot(myAddr >= 0) == 0ull) return;

  const float* featbase = x_img + (size_t)(((size_t)bn*NDD + d)*FHH*FWW)*NC
                        + ((size_t)w << 6) + c;
  float f[FHH];
  #pragma unroll
  for (int h=0; h<FHH; h++)
    f[h] = featbase[(size_t)h * (FWW*NC)];

  int prevAddr = -1;
  float acc = 0.0f;
  #pragma unroll
  for (int h=0; h<FHH; h++){
    const int a = __shfl(myAddr, h, 64);
    if (a != prevAddr){
      if (prevAddr >= 0) atomicAdd(scratch + (((size_t)prevAddr)<<6) + c, acc);
      acc = 0.0f;
      prevAddr = a;
    }
    if (a >= 0) acc += f[h];
  }
  if (prevAddr >= 0) atomicAdd(scratch + (((size_t)prevAddr)<<6) + c, acc);
}

// Transpose scratch (b, v, c) -> out (b, c, v), v = iy*NX0+ix (40000 per b).
// Block: 256 threads = 4 waves; tile = 64 voxels x 64 channels.
__global__ __launch_bounds__(256) void lss_transpose_kernel(
    const float* __restrict__ scratch, float* __restrict__ out)
{
  __shared__ float tile[64][65];
  const int tileIdx = blockIdx.x;            // 0..(4*625-1)
  const int b  = tileIdx / (NVOX/64);
  const int v0 = (tileIdx % (NVOX/64)) * 64;
  const int lane = threadIdx.x & 63;
  const int wv   = threadIdx.x >> 6;         // wave id 0..3

  const float* src = scratch + (((size_t)b*NVOX + v0) << 6);
  #pragma unroll
  for (int i=0; i<16; i++){
    const int r = wv*16 + i;                 // voxel row in tile
    tile[r][lane] = src[((size_t)r << 6) + lane];
  }
  __syncthreads();
  float* dst = out + ((size_t)b*NC)*NVOX + v0;
  #pragma unroll
  for (int i=0; i<16; i++){
    const int cc = wv*16 + i;                // channel row
    dst[(size_t)cc*NVOX + lane] = tile[lane][cc];
  }
}

// -------- fallback (small ws): direct atomics into out --------
__global__ __launch_bounds__(256) void lss_scatter_direct_kernel(
    const float* __restrict__ x_img, const double* __restrict__ ws,
    float* __restrict__ out)
{
  const int slab = blockIdx.x / 11;
  const int sub  = blockIdx.x % 11;
  const int t = sub*256 + (int)threadIdx.x;
  const int w = t >> 6;
  const int c = t & 63;
  const int b = slab / (NCAM*NDD);
  const int rem = slab % (NCAM*NDD);
  const int n = rem / NDD;
  const int d = rem % NDD;
  const int bn = b*NCAM + n;

  int myAddr = voxel_addr_for_lane(ws, bn, b, d, w, c);
  if (myAddr >= 0){
    const int iy = (myAddr / NX0) % NX1;
    const int ix = myAddr % NX0;
    myAddr = (((b*NC)*NX1 + iy)*NX0 + ix);
  }
  if (__ballot(myAddr >= 0) == 0ull) return;

  const float* featbase = x_img + (size_t)(((size_t)bn*NDD + d)*FHH*FWW)*NC
                        + ((size_t)w << 6) + c;
  float f[FHH];
  #pragma unroll
  for (int h=0; h<FHH; h++)
    f[h] = featbase[(size_t)h * (FWW*NC)];

  const int cOff = c * NVOX;
  int prevAddr = -1;
  float acc = 0.0f;
  #pragma unroll
  for (int h=0; h<FHH; h++){
    const int a = __shfl(myAddr, h, 64);
    const int addr = (a >= 0) ? (a + cOff) : -1;
    if (addr != prevAddr){
      if (prevAddr >= 0) atomicAdd(out + prevAddr, acc);
      acc = 0.0f;
      prevAddr = addr;
    }
    if (addr >= 0) acc += f[h];
  }
  if (prevAddr >= 0) atomicAdd(out + prevAddr, acc);
}

extern "C" void kernel_launch(void* const* d_in, const int* in_sizes, int n_in,
                              void* d_out, int out_size, void* d_ws, size_t ws_size,
                              hipStream_t stream) {
  const float* x_img      = (const float*)d_in[0];
  const float* rots       = (const float*)d_in[1];
  const float* trans      = (const float*)d_in[2];
  const float* intrins    = (const float*)d_in[3];
  const float* post_rots  = (const float*)d_in[4];
  const float* post_trans = (const float*)d_in[5];
  float* out = (float*)d_out;
  double* ws = (double*)d_ws;

  const int slabs = NB*NCAM*NDD;           // 984
  const size_t scratch_bytes = (size_t)NB * NVOX * NC * sizeof(float); // 40.96 MB
  const bool use_cf = ws_size >= SCRATCH_OFF_BYTES + scratch_bytes;

  lss_precompute_kernel<<<1, 64, 0, stream>>>(rots, intrins, post_rots,
                                              trans, post_trans, ws);
  if (use_cf) {
    float* scratch = (float*)((char*)d_ws + SCRATCH_OFF_BYTES);
    hipMemsetAsync(scratch, 0, scratch_bytes, stream);
    lss_scatter_cf_kernel<<<dim3(slabs*11), dim3(256), 0, stream>>>(x_img, ws, scratch);
    lss_transpose_kernel<<<dim3(NB*(NVOX/64)), dim3(256), 0, stream>>>(scratch, out);
  } else {
    hipMemsetAsync(out, 0, (size_t)out_size * sizeof(float), stream);
    lss_scatter_direct_kernel<<<dim3(slabs*11), dim3(256), 0, stream>>>(x_img, ws, out);
  }
}

// Round 6
// 51.436 us; speedup vs baseline: 3.1347x; 1.2144x over previous
//
#include <hip/hip_runtime.h>

// LiftSplatShoot: frustum geometry -> voxel scatter-add.
// f64 geometry (matches numpy f64 ref). Pipeline:
//   k0 (init): zero 41MB channel-fast scratch (float4 stores, 2500 blocks)
//              + per-(b,n) matrix precompute (1 block) -> ws
//   k1 (scatter): one wave per (b,n,d,w); lanes = channels. Lanes 0..15
//              compute f64 transform for h=lane -> voxel addr. ballot mask
//              gates per-h feature loads (wave-uniform). Register run-length
//              merge -> coalesced 64-lane atomic bursts into scratch(b,v,c).
//   k2 (transpose): LDS 64x64 tile, scratch(b,v,c) -> out(b,c,v).
// Fallback (small ws): direct strided atomics into out.

#define FHH 16
#define FWW 44
#define NDD 41
#define NCAM 6
#define NB 4
#define NC 64
#define NX0 200
#define NX1 200
#define NVOX (NX0*NX1)
#define SCRATCH_OFF_BYTES 8192
#define ZERO_BLOCKS 2500   // 2500 * 256 threads * 4 float4 = 10.24M floats

// 3x3 inverse in double: LU with partial pivoting + triangular solves.
__device__ void lu_inv3d(const double A[3][3], double out[3][3]) {
  double M[3][3]; int piv[3] = {0,1,2};
  for (int i=0;i<3;i++) for (int j=0;j<3;j++) M[i][j]=A[i][j];
  for (int k=0;k<3;k++){
    int p=k; double mx=fabs(M[k][k]);
    for (int r=k+1;r<3;r++){ double v=fabs(M[r][k]); if (v>mx){mx=v;p=r;} }
    if (p!=k){
      for (int j=0;j<3;j++){ double t=M[k][j]; M[k][j]=M[p][j]; M[p][j]=t; }
      int t=piv[k]; piv[k]=piv[p]; piv[p]=t;
    }
    for (int r=k+1;r<3;r++){
      double l = M[r][k] / M[k][k];
      M[r][k]=l;
      for (int j=k+1;j<3;j++) M[r][j] -= l*M[k][j];
    }
  }
  for (int col=0; col<3; col++){
    double bb[3];
    for (int i=0;i<3;i++) bb[i] = (piv[i]==col) ? 1.0 : 0.0;
    for (int i=1;i<3;i++){
      double acc=bb[i];
      for (int j=0;j<i;j++) acc -= M[i][j]*bb[j];
      bb[i]=acc;
    }
    for (int i=2;i>=0;i--){
      double acc=bb[i];
      for (int j=i+1;j<3;j++) acc -= M[i][j]*bb[j];
      bb[i]=acc / M[i][i];
    }
    out[0][col]=bb[0]; out[1][col]=bb[1]; out[2][col]=bb[2];
  }
}

// ws layout per bn (24 doubles): C[9], iPR[9], T[3], P[3]
__device__ void precompute_bn(
    const float* __restrict__ rots, const float* __restrict__ intrins,
    const float* __restrict__ post_rots, const float* __restrict__ trans,
    const float* __restrict__ post_trans, double* __restrict__ ws, int bn)
{
  double R[3][3], K[3][3], PR[3][3];
  for (int i=0;i<3;i++) for (int j=0;j<3;j++){
    R[i][j]=(double)rots[bn*9+i*3+j];
    K[i][j]=(double)intrins[bn*9+i*3+j];
    PR[i][j]=(double)post_rots[bn*9+i*3+j];
  }
  double iK[3][3], iPR[3][3];
  lu_inv3d(K, iK);
  lu_inv3d(PR, iPR);
  double* W = ws + bn*24;
  for (int i=0;i<3;i++) for (int j=0;j<3;j++){
    W[i*3+j]   = R[i][0]*iK[0][j] + R[i][1]*iK[1][j] + R[i][2]*iK[2][j];
    W[9+i*3+j] = iPR[i][j];
  }
  for (int i=0;i<3;i++){
    W[18+i] = (double)trans[bn*3+i];
    W[21+i] = (double)post_trans[bn*3+i];
  }
}

// k0: zero scratch + precompute matrices (one launch)
__global__ __launch_bounds__(256) void lss_init_kernel(
    const float* __restrict__ rots, const float* __restrict__ intrins,
    const float* __restrict__ post_rots, const float* __restrict__ trans,
    const float* __restrict__ post_trans,
    float* __restrict__ scratch, double* __restrict__ ws)
{
  if (blockIdx.x < ZERO_BLOCKS) {
    float4 z; z.x=0.f; z.y=0.f; z.z=0.f; z.w=0.f;
    float4* p = (float4*)scratch + (size_t)blockIdx.x*1024;
    const int t = threadIdx.x;
    p[t] = z; p[t+256] = z; p[t+512] = z; p[t+768] = z;
  } else {
    const int bn = threadIdx.x;
    if (bn < NB*NCAM)
      precompute_bn(rots, intrins, post_rots, trans, post_trans, ws, bn);
  }
}

// standalone precompute (fallback path)
__global__ __launch_bounds__(64) void lss_precompute_kernel(
    const float* __restrict__ rots, const float* __restrict__ intrins,
    const float* __restrict__ post_rots, const float* __restrict__ trans,
    const float* __restrict__ post_trans, double* __restrict__ ws)
{
  const int bn = threadIdx.x;
  if (bn < NB*NCAM)
    precompute_bn(rots, intrins, post_rots, trans, post_trans, ws, bn);
}

// Spatial voxel index (b*NX1+iy)*NX0+ix for h=lane (lanes 0..15), else -1.
__device__ __forceinline__ int voxel_addr_for_lane(
    const double* __restrict__ ws, int bn, int b, int d, int w, int lane)
{
  if (lane >= FHH) return -1;
  const double* W = ws + bn*24;
  const double u  = (double)w * (703.0/43.0);
  const double v  = (double)lane * 17.0;
  const double dd = (double)(4 + d);
  const double p0x = u  - W[21];
  const double p0y = v  - W[22];
  const double p0z = dd - W[23];
  const double p1x = W[9+0]*p0x + W[9+1]*p0y + W[9+2]*p0z;
  const double p1y = W[9+3]*p0x + W[9+4]*p0y + W[9+5]*p0z;
  const double p1z = W[9+6]*p0x + W[9+7]*p0y + W[9+8]*p0z;
  const double p2x = p1x * p1z;
  const double p2y = p1y * p1z;
  const double p2z = p1z;
  const double gx = W[0]*p2x + W[1]*p2y + W[2]*p2z + W[18];
  const double gy = W[3]*p2x + W[4]*p2y + W[5]*p2z + W[19];
  const double gz = W[6]*p2x + W[7]*p2y + W[8]*p2z + W[20];
  const double tx = (gx + 50.0) / 0.5;
  const double ty = (gy + 50.0) / 0.5;
  const double tz = (gz + 10.0) / 20.0;
  const int ix = (int)tx;
  const int iy = (int)ty;
  const int iz = (int)tz;
  const bool kept = (ix>=0) && (ix<NX0) && (iy>=0) && (iy<NX1) && (iz==0);
  return kept ? ((b*NX1 + iy)*NX0 + ix) : -1;
}

// k1: scatter into channel-fast scratch: scratch[(vox<<6)+c]
__global__ __launch_bounds__(256) void lss_scatter_cf_kernel(
    const float* __restrict__ x_img, const double* __restrict__ ws,
    float* __restrict__ scratch)
{
  const int slab = blockIdx.x / 11;
  const int sub  = blockIdx.x % 11;
  const int t = sub*256 + (int)threadIdx.x;
  const int w = t >> 6;
  const int c = t & 63;
  const int b = slab / (NCAM*NDD);
  const int rem = slab % (NCAM*NDD);
  const int n = rem / NDD;
  const int d = rem % NDD;
  const int bn = b*NCAM + n;

  const int myAddr = voxel_addr_for_lane(ws, bn, b, d, w, c);
  const unsigned long long keptMask = __ballot(myAddr >= 0);
  if (keptMask == 0ull) return;

  const float* featbase = x_img + (size_t)(((size_t)bn*NDD + d)*FHH*FWW)*NC
                        + ((size_t)w << 6) + c;

  // loads gated per-h by wave-uniform mask bit (scalar branch, pipelined)
  float f[FHH];
  #pragma unroll
  for (int h=0; h<FHH; h++)
    if (keptMask & (1ull<<h))
      f[h] = featbase[(size_t)h * (FWW*NC)];

  int prevAddr = -1;
  float acc = 0.0f;
  #pragma unroll
  for (int h=0; h<FHH; h++){
    const int a = __shfl(myAddr, h, 64);
    if (a != prevAddr){
      if (prevAddr >= 0) atomicAdd(scratch + (((size_t)prevAddr)<<6) + c, acc);
      acc = 0.0f;
      prevAddr = a;
    }
    if (a >= 0) acc += f[h];
  }
  if (prevAddr >= 0) atomicAdd(scratch + (((size_t)prevAddr)<<6) + c, acc);
}

// k2: transpose scratch (b, v, c) -> out (b, c, v)
__global__ __launch_bounds__(256) void lss_transpose_kernel(
    const float* __restrict__ scratch, float* __restrict__ out)
{
  __shared__ float tile[64][65];
  const int tileIdx = blockIdx.x;            // 0..(4*625-1)
  const int b  = tileIdx / (NVOX/64);
  const int v0 = (tileIdx % (NVOX/64)) * 64;
  const int lane = threadIdx.x & 63;
  const int wv   = threadIdx.x >> 6;         // wave id 0..3

  const float* src = scratch + (((size_t)b*NVOX + v0) << 6);
  #pragma unroll
  for (int i=0; i<16; i++){
    const int r = wv*16 + i;
    tile[r][lane] = src[((size_t)r << 6) + lane];
  }
  __syncthreads();
  float* dst = out + ((size_t)b*NC)*NVOX + v0;
  #pragma unroll
  for (int i=0; i<16; i++){
    const int cc = wv*16 + i;
    dst[(size_t)cc*NVOX + lane] = tile[lane][cc];
  }
}

// -------- fallback (small ws): direct atomics into out --------
__global__ __launch_bounds__(256) void lss_scatter_direct_kernel(
    const float* __restrict__ x_img, const double* __restrict__ ws,
    float* __restrict__ out)
{
  const int slab = blockIdx.x / 11;
  const int sub  = blockIdx.x % 11;
  const int t = sub*256 + (int)threadIdx.x;
  const int w = t >> 6;
  const int c = t & 63;
  const int b = slab / (NCAM*NDD);
  const int rem = slab % (NCAM*NDD);
  const int n = rem / NDD;
  const int d = rem % NDD;
  const int bn = b*NCAM + n;

  int myAddr = voxel_addr_for_lane(ws, bn, b, d, w, c);
  if (myAddr >= 0){
    const int iy = (myAddr / NX0) % NX1;
    const int ix = myAddr % NX0;
    myAddr = (((b*NC)*NX1 + iy)*NX0 + ix);
  }
  if (__ballot(myAddr >= 0) == 0ull) return;

  const float* featbase = x_img + (size_t)(((size_t)bn*NDD + d)*FHH*FWW)*NC
                        + ((size_t)w << 6) + c;
  float f[FHH];
  #pragma unroll
  for (int h=0; h<FHH; h++)
    f[h] = featbase[(size_t)h * (FWW*NC)];

  const int cOff = c * NVOX;
  int prevAddr = -1;
  float acc = 0.0f;
  #pragma unroll
  for (int h=0; h<FHH; h++){
    const int a = __shfl(myAddr, h, 64);
    const int addr = (a >= 0) ? (a + cOff) : -1;
    if (addr != prevAddr){
      if (prevAddr >= 0) atomicAdd(out + prevAddr, acc);
      acc = 0.0f;
      prevAddr = addr;
    }
    if (addr >= 0) acc += f[h];
  }
  if (prevAddr >= 0) atomicAdd(out + prevAddr, acc);
}

extern "C" void kernel_launch(void* const* d_in, const int* in_sizes, int n_in,
                              void* d_out, int out_size, void* d_ws, size_t ws_size,
                              hipStream_t stream) {
  const float* x_img      = (const float*)d_in[0];
  const float* rots       = (const float*)d_in[1];
  const float* trans      = (const float*)d_in[2];
  const float* intrins    = (const float*)d_in[3];
  const float* post_rots  = (const float*)d_in[4];
  const float* post_trans = (const float*)d_in[5];
  float* out = (float*)d_out;
  double* ws = (double*)d_ws;

  const int slabs = NB*NCAM*NDD;           // 984
  const size_t scratch_bytes = (size_t)NB * NVOX * NC * sizeof(float); // 40.96 MB
  const bool use_cf = ws_size >= SCRATCH_OFF_BYTES + scratch_bytes;

  if (use_cf) {
    float* scratch = (float*)((char*)d_ws + SCRATCH_OFF_BYTES);
    lss_init_kernel<<<dim3(ZERO_BLOCKS+1), dim3(256), 0, stream>>>(
        rots, intrins, post_rots, trans, post_trans, scratch, ws);
    lss_scatter_cf_kernel<<<dim3(slabs*11), dim3(256), 0, stream>>>(x_img, ws, scratch);
    lss_transpose_kernel<<<dim3(NB*(NVOX/64)), dim3(256), 0, stream>>>(scratch, out);
  } else {
    hipMemsetAsync(out, 0, (size_t)out_size * sizeof(float), stream);
    lss_precompute_kernel<<<1, 64, 0, stream>>>(rots, intrins, post_rots,
                                                trans, post_trans, ws);
    lss_scatter_direct_kernel<<<dim3(slabs*11), dim3(256), 0, stream>>>(x_img, ws, out);
  }
}

// Round 7
// 50.635 us; speedup vs baseline: 3.1842x; 1.0158x over previous
//
#include <hip/hip_runtime.h>

// LiftSplatShoot: frustum geometry -> voxel scatter-add.
// f64 geometry (matches numpy f64 ref). Pipeline:
//   k0 (init): zero 41MB channel-fast scratch (float4 stores) + per-(b,n)
//              matrix precompute -> ws
//   k1 (scatter): one wave per (b,n,d,w); lanes = channels. Lanes 0..15
//              compute f64 transform for h=lane -> voxel addr. Register
//              run-length merge -> coalesced 64-lane atomic bursts into
//              scratch(b,v,c). XCD-chunked blockIdx swizzle keeps adjacent-d
//              slabs (overlapping voxel lines) on one XCD's L2.
//   k2 (transpose): LDS 64x64 tile, scratch(b,v,c) -> out(b,c,v).
// Fallback (small ws): direct strided atomics into out.

#define FHH 16
#define FWW 44
#define NDD 41
#define NCAM 6
#define NB 4
#define NC 64
#define NX0 200
#define NX1 200
#define NVOX (NX0*NX1)
#define SCRATCH_OFF_BYTES 8192
#define ZERO_BLOCKS 2500   // 2500 * 256 threads * 4 float4 = 10.24M floats
#define NXCD 8
#define SCATTER_BLOCKS (NB*NCAM*NDD*11)   // 10824 = 8 * 1353

// 3x3 inverse in double: LU with partial pivoting + triangular solves.
__device__ void lu_inv3d(const double A[3][3], double out[3][3]) {
  double M[3][3]; int piv[3] = {0,1,2};
  for (int i=0;i<3;i++) for (int j=0;j<3;j++) M[i][j]=A[i][j];
  for (int k=0;k<3;k++){
    int p=k; double mx=fabs(M[k][k]);
    for (int r=k+1;r<3;r++){ double v=fabs(M[r][k]); if (v>mx){mx=v;p=r;} }
    if (p!=k){
      for (int j=0;j<3;j++){ double t=M[k][j]; M[k][j]=M[p][j]; M[p][j]=t; }
      int t=piv[k]; piv[k]=piv[p]; piv[p]=t;
    }
    for (int r=k+1;r<3;r++){
      double l = M[r][k] / M[k][k];
      M[r][k]=l;
      for (int j=k+1;j<3;j++) M[r][j] -= l*M[k][j];
    }
  }
  for (int col=0; col<3; col++){
    double bb[3];
    for (int i=0;i<3;i++) bb[i] = (piv[i]==col) ? 1.0 : 0.0;
    for (int i=1;i<3;i++){
      double acc=bb[i];
      for (int j=0;j<i;j++) acc -= M[i][j]*bb[j];
      bb[i]=acc;
    }
    for (int i=2;i>=0;i--){
      double acc=bb[i];
      for (int j=i+1;j<3;j++) acc -= M[i][j]*bb[j];
      bb[i]=acc / M[i][i];
    }
    out[0][col]=bb[0]; out[1][col]=bb[1]; out[2][col]=bb[2];
  }
}

// ws layout per bn (24 doubles): C[9], iPR[9], T[3], P[3]
__device__ void precompute_bn(
    const float* __restrict__ rots, const float* __restrict__ intrins,
    const float* __restrict__ post_rots, const float* __restrict__ trans,
    const float* __restrict__ post_trans, double* __restrict__ ws, int bn)
{
  double R[3][3], K[3][3], PR[3][3];
  for (int i=0;i<3;i++) for (int j=0;j<3;j++){
    R[i][j]=(double)rots[bn*9+i*3+j];
    K[i][j]=(double)intrins[bn*9+i*3+j];
    PR[i][j]=(double)post_rots[bn*9+i*3+j];
  }
  double iK[3][3], iPR[3][3];
  lu_inv3d(K, iK);
  lu_inv3d(PR, iPR);
  double* W = ws + bn*24;
  for (int i=0;i<3;i++) for (int j=0;j<3;j++){
    W[i*3+j]   = R[i][0]*iK[0][j] + R[i][1]*iK[1][j] + R[i][2]*iK[2][j];
    W[9+i*3+j] = iPR[i][j];
  }
  for (int i=0;i<3;i++){
    W[18+i] = (double)trans[bn*3+i];
    W[21+i] = (double)post_trans[bn*3+i];
  }
}

// k0: zero scratch + precompute matrices (one launch)
__global__ __launch_bounds__(256) void lss_init_kernel(
    const float* __restrict__ rots, const float* __restrict__ intrins,
    const float* __restrict__ post_rots, const float* __restrict__ trans,
    const float* __restrict__ post_trans,
    float* __restrict__ scratch, double* __restrict__ ws)
{
  if (blockIdx.x < ZERO_BLOCKS) {
    float4 z; z.x=0.f; z.y=0.f; z.z=0.f; z.w=0.f;
    float4* p = (float4*)scratch + (size_t)blockIdx.x*1024;
    const int t = threadIdx.x;
    p[t] = z; p[t+256] = z; p[t+512] = z; p[t+768] = z;
  } else {
    const int bn = threadIdx.x;
    if (bn < NB*NCAM)
      precompute_bn(rots, intrins, post_rots, trans, post_trans, ws, bn);
  }
}

// standalone precompute (fallback path)
__global__ __launch_bounds__(64) void lss_precompute_kernel(
    const float* __restrict__ rots, const float* __restrict__ intrins,
    const float* __restrict__ post_rots, const float* __restrict__ trans,
    const float* __restrict__ post_trans, double* __restrict__ ws)
{
  const int bn = threadIdx.x;
  if (bn < NB*NCAM)
    precompute_bn(rots, intrins, post_rots, trans, post_trans, ws, bn);
}

// Spatial voxel index (b*NX1+iy)*NX0+ix for h=lane (lanes 0..15), else -1.
__device__ __forceinline__ int voxel_addr_for_lane(
    const double* __restrict__ ws, int bn, int b, int d, int w, int lane)
{
  if (lane >= FHH) return -1;
  const double* W = ws + bn*24;
  const double u  = (double)w * (703.0/43.0);
  const double v  = (double)lane * 17.0;
  const double dd = (double)(4 + d);
  const double p0x = u  - W[21];
  const double p0y = v  - W[22];
  const double p0z = dd - W[23];
  const double p1x = W[9+0]*p0x + W[9+1]*p0y + W[9+2]*p0z;
  const double p1y = W[9+3]*p0x + W[9+4]*p0y + W[9+5]*p0z;
  const double p1z = W[9+6]*p0x + W[9+7]*p0y + W[9+8]*p0z;
  const double p2x = p1x * p1z;
  const double p2y = p1y * p1z;
  const double p2z = p1z;
  const double gx = W[0]*p2x + W[1]*p2y + W[2]*p2z + W[18];
  const double gy = W[3]*p2x + W[4]*p2y + W[5]*p2z + W[19];
  const double gz = W[6]*p2x + W[7]*p2y + W[8]*p2z + W[20];
  const double tx = (gx + 50.0) / 0.5;
  const double ty = (gy + 50.0) / 0.5;
  const double tz = (gz + 10.0) / 20.0;
  const int ix = (int)tx;
  const int iy = (int)ty;
  const int iz = (int)tz;
  const bool kept = (ix>=0) && (ix<NX0) && (iy>=0) && (iy<NX1) && (iz==0);
  return kept ? ((b*NX1 + iy)*NX0 + ix) : -1;
}

// k1: scatter into channel-fast scratch: scratch[(vox<<6)+c]
__global__ __launch_bounds__(256) void lss_scatter_cf_kernel(
    const float* __restrict__ x_img, const double* __restrict__ ws,
    float* __restrict__ scratch)
{
  // XCD-chunked bijective swizzle: physical blocks p = k, k+8, k+16, ...
  // (which the dispatcher round-robins onto XCD k) receive CONTIGUOUS
  // logical work [k*1353, (k+1)*1353) -> adjacent-d slabs share one L2.
  const int bid = (int)((blockIdx.x % NXCD) * (SCATTER_BLOCKS/NXCD)
                        + blockIdx.x / NXCD);
  const int slab = bid / 11;
  const int sub  = bid % 11;
  const int t = sub*256 + (int)threadIdx.x;
  const int w = t >> 6;
  const int c = t & 63;
  const int b = slab / (NCAM*NDD);
  const int rem = slab % (NCAM*NDD);
  const int n = rem / NDD;
  const int d = rem % NDD;
  const int bn = b*NCAM + n;

  const int myAddr = voxel_addr_for_lane(ws, bn, b, d, w, c);
  const unsigned long long keptMask = __ballot(myAddr >= 0);
  if (keptMask == 0ull) return;

  const float* featbase = x_img + (size_t)(((size_t)bn*NDD + d)*FHH*FWW)*NC
                        + ((size_t)w << 6) + c;

  // loads gated per-h by wave-uniform mask bit (scalar branch, pipelined)
  float f[FHH];
  #pragma unroll
  for (int h=0; h<FHH; h++)
    if (keptMask & (1ull<<h))
      f[h] = featbase[(size_t)h * (FWW*NC)];

  int prevAddr = -1;
  float acc = 0.0f;
  #pragma unroll
  for (int h=0; h<FHH; h++){
    const int a = __shfl(myAddr, h, 64);
    if (a != prevAddr){
      if (prevAddr >= 0) atomicAdd(scratch + (((size_t)prevAddr)<<6) + c, acc);
      acc = 0.0f;
      prevAddr = a;
    }
    if (a >= 0) acc += f[h];
  }
  if (prevAddr >= 0) atomicAdd(scratch + (((size_t)prevAddr)<<6) + c, acc);
}

// k2: transpose scratch (b, v, c) -> out (b, c, v)
__global__ __launch_bounds__(256) void lss_transpose_kernel(
    const float* __restrict__ scratch, float* __restrict__ out)
{
  __shared__ float tile[64][65];
  const int tileIdx = blockIdx.x;            // 0..(4*625-1)
  const int b  = tileIdx / (NVOX/64);
  const int v0 = (tileIdx % (NVOX/64)) * 64;
  const int lane = threadIdx.x & 63;
  const int wv   = threadIdx.x >> 6;         // wave id 0..3

  const float* src = scratch + (((size_t)b*NVOX + v0) << 6);
  #pragma unroll
  for (int i=0; i<16; i++){
    const int r = wv*16 + i;
    tile[r][lane] = src[((size_t)r << 6) + lane];
  }
  __syncthreads();
  float* dst = out + ((size_t)b*NC)*NVOX + v0;
  #pragma unroll
  for (int i=0; i<16; i++){
    const int cc = wv*16 + i;
    dst[(size_t)cc*NVOX + lane] = tile[lane][cc];
  }
}

// -------- fallback (small ws): direct atomics into out --------
__global__ __launch_bounds__(256) void lss_scatter_direct_kernel(
    const float* __restrict__ x_img, const double* __restrict__ ws,
    float* __restrict__ out)
{
  const int slab = blockIdx.x / 11;
  const int sub  = blockIdx.x % 11;
  const int t = sub*256 + (int)threadIdx.x;
  const int w = t >> 6;
  const int c = t & 63;
  const int b = slab / (NCAM*NDD);
  const int rem = slab % (NCAM*NDD);
  const int n = rem / NDD;
  const int d = rem % NDD;
  const int bn = b*NCAM + n;

  int myAddr = voxel_addr_for_lane(ws, bn, b, d, w, c);
  if (myAddr >= 0){
    const int iy = (myAddr / NX0) % NX1;
    const int ix = myAddr % NX0;
    myAddr = (((b*NC)*NX1 + iy)*NX0 + ix);
  }
  if (__ballot(myAddr >= 0) == 0ull) return;

  const float* featbase = x_img + (size_t)(((size_t)bn*NDD + d)*FHH*FWW)*NC
                        + ((size_t)w << 6) + c;
  float f[FHH];
  #pragma unroll
  for (int h=0; h<FHH; h++)
    f[h] = featbase[(size_t)h * (FWW*NC)];

  const int cOff = c * NVOX;
  int prevAddr = -1;
  float acc = 0.0f;
  #pragma unroll
  for (int h=0; h<FHH; h++){
    const int a = __shfl(myAddr, h, 64);
    const int addr = (a >= 0) ? (a + cOff) : -1;
    if (addr != prevAddr){
      if (prevAddr >= 0) atomicAdd(out + prevAddr, acc);
      acc = 0.0f;
      prevAddr = addr;
    }
    if (addr >= 0) acc += f[h];
  }
  if (prevAddr >= 0) atomicAdd(out + prevAddr, acc);
}

extern "C" void kernel_launch(void* const* d_in, const int* in_sizes, int n_in,
                              void* d_out, int out_size, void* d_ws, size_t ws_size,
                              hipStream_t stream) {
  const float* x_img      = (const float*)d_in[0];
  const float* rots       = (const float*)d_in[1];
  const float* trans      = (const float*)d_in[2];
  const float* intrins    = (const float*)d_in[3];
  const float* post_rots  = (const float*)d_in[4];
  const float* post_trans = (const float*)d_in[5];
  float* out = (float*)d_out;
  double* ws = (double*)d_ws;

  const size_t scratch_bytes = (size_t)NB * NVOX * NC * sizeof(float); // 40.96 MB
  const bool use_cf = ws_size >= SCRATCH_OFF_BYTES + scratch_bytes;

  if (use_cf) {
    float* scratch = (float*)((char*)d_ws + SCRATCH_OFF_BYTES);
    lss_init_kernel<<<dim3(ZERO_BLOCKS+1), dim3(256), 0, stream>>>(
        rots, intrins, post_rots, trans, post_trans, scratch, ws);
    lss_scatter_cf_kernel<<<dim3(SCATTER_BLOCKS), dim3(256), 0, stream>>>(x_img, ws, scratch);
    lss_transpose_kernel<<<dim3(NB*(NVOX/64)), dim3(256), 0, stream>>>(scratch, out);
  } else {
    hipMemsetAsync(out, 0, (size_t)out_size * sizeof(float), stream);
    lss_precompute_kernel<<<1, 64, 0, stream>>>(rots, intrins, post_rots,
                                                trans, post_trans, ws);
    lss_scatter_direct_kernel<<<dim3(NB*NCAM*NDD*11), dim3(256), 0, stream>>>(x_img, ws, out);
  }
}